// Round 1
// baseline (451.349 us; speedup 1.0000x reference)
//
#include <hip/hip_runtime.h>

typedef unsigned short u16;
typedef __bf16 bf16x8 __attribute__((ext_vector_type(8)));
typedef float f32x4 __attribute__((ext_vector_type(4)));
typedef unsigned short u16x4 __attribute__((ext_vector_type(4)));
typedef unsigned short u16x8 __attribute__((ext_vector_type(8)));

#define LOG2E 1.44269504088896340736f

__device__ __forceinline__ u16 f2bf(float f) {
  unsigned u = __float_as_uint(f);
  u += 0x7FFFu + ((u >> 16) & 1u);
  return (u16)(u >> 16);
}

__device__ __forceinline__ void load_lds16(const void* g, void* l) {
  __builtin_amdgcn_global_load_lds(
      (__attribute__((address_space(1))) void*)g,
      (__attribute__((address_space(3))) void*)l, 16, 0, 0);
}

__device__ __forceinline__ f32x4 mfma16(bf16x8 a, bf16x8 b, f32x4 c) {
  return __builtin_amdgcn_mfma_f32_16x16x32_bf16(a, b, c, 0, 0, 0);
}

// ---------------- cast fp32 -> bf16 (vectorized) ----------------
__global__ __launch_bounds__(256) void cast_bf16_kernel(const float* __restrict__ x,
                                                        u16* __restrict__ y, int n4) {
  int i = blockIdx.x * 256 + threadIdx.x;
  if (i >= n4) return;
  const float4 v = ((const float4*)x)[i];
  u16x4 o;
  o.x = f2bf(v.x); o.y = f2bf(v.y); o.z = f2bf(v.z); o.w = f2bf(v.w);
  ((u16x4*)y)[i] = o;
}

// ---------------- transpose + cast weights: W[K,N] f32 -> Wt[N,K] bf16 ----------------
__global__ __launch_bounds__(256) void transpose_cast_kernel(const float* __restrict__ W,
                                                             u16* __restrict__ Wt,
                                                             int K, int N) {
  __shared__ float tile[32][33];
  const int tx = threadIdx.x, ty = threadIdx.y;  // (32,8)
  const int n0 = blockIdx.x * 32, k0 = blockIdx.y * 32;
#pragma unroll
  for (int i = 0; i < 4; i++)
    tile[ty + i * 8][tx] = W[(size_t)(k0 + ty + i * 8) * N + n0 + tx];
  __syncthreads();
#pragma unroll
  for (int i = 0; i < 4; i++)
    Wt[(size_t)(n0 + ty + i * 8) * K + k0 + tx] = f2bf(tile[tx][ty + i * 8]);
}

// ---------------- bf16 MFMA GEMM: C[M,N] = A[M,K] @ Bt[N,K]^T + bias ----------------
// Cb (bf16 out) or Cf (fp32 out, += resid). 128x128 tile, 4 waves, BK=32.
__global__ __launch_bounds__(256) void gemm_bf16_kernel(
    const u16* __restrict__ A, const u16* __restrict__ Bt,
    const float* __restrict__ bias, const float* __restrict__ resid,
    u16* __restrict__ Cb, float* __restrict__ Cf, int M, int N, int K) {
  __shared__ alignas(16) u16 As[128 * 32];
  __shared__ alignas(16) u16 Bs[128 * 32];
  const int tid = threadIdx.x;
  const int wave = tid >> 6, lane = tid & 63;
  const int lm = lane & 15, kq = lane >> 4;
  const int bm = blockIdx.y * 128, bn = blockIdx.x * 128;
  const int g1 = tid, g2 = tid + 256;
  const u16* Ag1 = A + (size_t)(bm + (g1 >> 2)) * K + (g1 & 3) * 8;
  const u16* Ag2 = A + (size_t)(bm + (g2 >> 2)) * K + (g2 & 3) * 8;
  const u16* Bg1 = Bt + (size_t)(bn + (g1 >> 2)) * K + (g1 & 3) * 8;
  const u16* Bg2 = Bt + (size_t)(bn + (g2 >> 2)) * K + (g2 & 3) * 8;
  u16* lA1 = &As[g1 * 8]; u16* lA2 = &As[g2 * 8];
  u16* lB1 = &Bs[g1 * 8]; u16* lB2 = &Bs[g2 * 8];
  const int wm = (wave >> 1) * 64, wn = (wave & 1) * 64;

  f32x4 acc[4][4] = {};
  for (int k0 = 0; k0 < K; k0 += 32) {
    __syncthreads();
    load_lds16(Ag1 + k0, lA1);
    load_lds16(Ag2 + k0, lA2);
    load_lds16(Bg1 + k0, lB1);
    load_lds16(Bg2 + k0, lB2);
    __syncthreads();
    bf16x8 a[4], b[4];
#pragma unroll
    for (int t = 0; t < 4; t++)
      a[t] = *(const bf16x8*)&As[(wm + t * 16 + lm) * 32 + kq * 8];
#pragma unroll
    for (int t = 0; t < 4; t++)
      b[t] = *(const bf16x8*)&Bs[(wn + t * 16 + lm) * 32 + kq * 8];
#pragma unroll
    for (int mt = 0; mt < 4; mt++)
#pragma unroll
      for (int nt = 0; nt < 4; nt++)
        acc[mt][nt] = mfma16(a[mt], b[nt], acc[mt][nt]);
  }
  // epilogue: C/D layout col=lane&15, row=(lane>>4)*4+r
#pragma unroll
  for (int mt = 0; mt < 4; mt++) {
#pragma unroll
    for (int nt = 0; nt < 4; nt++) {
      const int col = bn + wn + nt * 16 + lm;
      const float bv = bias[col];
#pragma unroll
      for (int r = 0; r < 4; r++) {
        const int row = bm + wm + mt * 16 + kq * 4 + r;
        const size_t idx = (size_t)row * N + col;
        const float v = acc[mt][nt][r] + bv;
        if (Cf) {
          Cf[idx] = v + resid[idx];
        } else {
          Cb[idx] = f2bf(v);
        }
      }
    }
  }
}

// ---------------- flash attention: per block (b, h, 64 q-rows), BKV=64 ----------------
__global__ __launch_bounds__(256) void attn_kernel(
    const u16* __restrict__ Qp, const u16* __restrict__ Kp,
    const u16* __restrict__ Vp, u16* __restrict__ ctx) {
  __shared__ alignas(16) u16 Ks[64 * 64];      // [kv][hd]
  __shared__ alignas(16) u16 Vt[64 * 64];      // [hd][kv]
  __shared__ alignas(16) u16 Ps[4][16 * 64];   // per-wave P [q][kv]
  const int tid = threadIdx.x;
  const int wave = tid >> 6, lane = tid & 63;
  const int lm = lane & 15, kq = lane >> 4;
  const int b = blockIdx.z, h = blockIdx.y;
  const int q0 = blockIdx.x * 64 + wave * 16;

  // Q fragments (B-operand layout: n=q=lm, k=hd=kq*8+j), straight from global
  const u16* qrow = Qp + (size_t)(b * 2048 + q0 + lm) * 1024 + h * 64;
  const bf16x8 qf0 = *(const bf16x8*)(qrow + kq * 8);
  const bf16x8 qf1 = *(const bf16x8*)(qrow + 32 + kq * 8);

  const u16* Kbase = Kp + (size_t)(b * 2048) * 1024 + h * 64;
  const u16* Vbase = Vp + (size_t)(b * 2048) * 1024 + h * 64;
  const int g1 = tid, g2 = tid + 256;
  const int vkv = tid >> 3, vh0 = (tid & 7) * 8;

  f32x4 o[4] = {};
  float mrow = -1e30f, lrow = 0.f;

  for (int kv0 = 0; kv0 < 2048; kv0 += 64) {
    __syncthreads();
    // stage K tile [64kv x 64hd] via async global->LDS (lane-contiguous granules)
    load_lds16(Kbase + (size_t)(kv0 + (g1 >> 3)) * 1024 + (g1 & 7) * 8, &Ks[g1 * 8]);
    load_lds16(Kbase + (size_t)(kv0 + (g2 >> 3)) * 1024 + (g2 & 7) * 8, &Ks[g2 * 8]);
    // stage V transposed: Vt[hd][kv]
    const u16x8 va = *(const u16x8*)(Vbase + (size_t)(kv0 + vkv) * 1024 + vh0);
    const u16x8 vb = *(const u16x8*)(Vbase + (size_t)(kv0 + vkv + 32) * 1024 + vh0);
#pragma unroll
    for (int j = 0; j < 8; j++) {
      Vt[(vh0 + j) * 64 + vkv] = va[j];
      Vt[(vh0 + j) * 64 + vkv + 32] = vb[j];
    }
    __syncthreads();

    // S^T = K . Q^T : D[m=kv][n=q];  C-layout: col=q=lm, row=kv=kq*4+r (+16*kb)
    f32x4 st[4] = {};
#pragma unroll
    for (int s = 0; s < 2; s++) {
      const bf16x8 qf = s ? qf1 : qf0;
#pragma unroll
      for (int kb = 0; kb < 4; kb++) {
        const bf16x8 kf = *(const bf16x8*)&Ks[(kb * 16 + lm) * 64 + s * 32 + kq * 8];
        st[kb] = mfma16(kf, qf, st[kb]);
      }
    }
    // online softmax (per q = lm; my 16 values are 16 distinct kv for that q)
    float smax = -1e30f;
#pragma unroll
    for (int kb = 0; kb < 4; kb++)
#pragma unroll
      for (int r = 0; r < 4; r++) {
        st[kb][r] *= 0.125f;
        smax = fmaxf(smax, st[kb][r]);
      }
    smax = fmaxf(smax, __shfl_xor(smax, 16));
    smax = fmaxf(smax, __shfl_xor(smax, 32));
    const float mnew = fmaxf(mrow, smax);
    const float alpha = __builtin_amdgcn_exp2f((mrow - mnew) * LOG2E);
    float lsum = 0.f;
#pragma unroll
    for (int kb = 0; kb < 4; kb++) {
      u16x4 pl;
#pragma unroll
      for (int r = 0; r < 4; r++) {
        const float p = __builtin_amdgcn_exp2f((st[kb][r] - mnew) * LOG2E);
        lsum += p;
        pl[r] = f2bf(p);
      }
      // P^T in C-layout -> P[q][kv] in LDS (4 consecutive kv = 8B store)
      *(u16x4*)&Ps[wave][lm * 64 + kb * 16 + kq * 4] = pl;
    }
    lsum += __shfl_xor(lsum, 16);
    lsum += __shfl_xor(lsum, 32);
    lrow = lrow * alpha + lsum;
    mrow = mnew;

    // rescale O (O rows are q=kq*4+r -> fetch alpha from lane q)
    float ar[4];
#pragma unroll
    for (int r = 0; r < 4; r++) ar[r] = __shfl(alpha, kq * 4 + r);
#pragma unroll
    for (int blk = 0; blk < 4; blk++)
#pragma unroll
      for (int r = 0; r < 4; r++) o[blk][r] *= ar[r];

    // O += P . V  (A = P[q][kv] from LDS, B = V^T[hd][kv] from LDS)
#pragma unroll
    for (int s2 = 0; s2 < 2; s2++) {
      const bf16x8 pf = *(const bf16x8*)&Ps[wave][lm * 64 + s2 * 32 + kq * 8];
#pragma unroll
      for (int blk = 0; blk < 4; blk++) {
        const bf16x8 vf = *(const bf16x8*)&Vt[(blk * 16 + lm) * 64 + s2 * 32 + kq * 8];
        o[blk] = mfma16(pf, vf, o[blk]);
      }
    }
  }
  // final normalize + store ctx bf16: row=b*2048+q0+kq*4+r, col=h*64+blk*16+lm
  float lr[4];
#pragma unroll
  for (int r = 0; r < 4; r++) lr[r] = 1.f / __shfl(lrow, kq * 4 + r);
#pragma unroll
  for (int blk = 0; blk < 4; blk++)
#pragma unroll
    for (int r = 0; r < 4; r++) {
      const size_t row = (size_t)(b * 2048 + q0 + kq * 4 + r);
      ctx[row * 1024 + h * 64 + blk * 16 + lm] = f2bf(o[blk][r] * lr[r]);
    }
}

// ---------------- LayerNorm over last dim (1024), one block per row ----------------
__global__ __launch_bounds__(256) void ln_kernel(const float* __restrict__ x,
                                                 const float* __restrict__ gamma,
                                                 const float* __restrict__ beta,
                                                 float* __restrict__ out) {
  const int row = blockIdx.x;
  const int t = threadIdx.x;
  const float4 v = ((const float4*)(x + (size_t)row * 1024))[t];
  float s = v.x + v.y + v.z + v.w;
  float s2 = v.x * v.x + v.y * v.y + v.z * v.z + v.w * v.w;
#pragma unroll
  for (int m = 1; m < 64; m <<= 1) {
    s += __shfl_xor(s, m);
    s2 += __shfl_xor(s2, m);
  }
  __shared__ float red[8];
  const int wave = t >> 6, lane = t & 63;
  if (lane == 0) { red[wave] = s; red[4 + wave] = s2; }
  __syncthreads();
  s = red[0] + red[1] + red[2] + red[3];
  s2 = red[4] + red[5] + red[6] + red[7];
  const float mu = s * (1.f / 1024.f);
  const float var = s2 * (1.f / 1024.f) - mu * mu;
  const float rstd = rsqrtf(var + 1e-5f);
  const float4 gm = ((const float4*)gamma)[t];
  const float4 bt = ((const float4*)beta)[t];
  float4 o;
  o.x = (v.x - mu) * rstd * gm.x + bt.x;
  o.y = (v.y - mu) * rstd * gm.y + bt.y;
  o.z = (v.z - mu) * rstd * gm.z + bt.z;
  o.w = (v.w - mu) * rstd * gm.w + bt.w;
  ((float4*)(out + (size_t)row * 1024))[t] = o;
}

extern "C" void kernel_launch(void* const* d_in, const int* in_sizes, int n_in,
                              void* d_out, int out_size, void* d_ws, size_t ws_size,
                              hipStream_t stream) {
  const float* query     = (const float*)d_in[0];
  const float* key_value = (const float*)d_in[1];
  const float* Wq = (const float*)d_in[2];
  const float* bq = (const float*)d_in[3];
  const float* Wk = (const float*)d_in[4];
  const float* bk = (const float*)d_in[5];
  const float* Wv = (const float*)d_in[6];
  const float* bv = (const float*)d_in[7];
  const float* Wo = (const float*)d_in[8];
  const float* bo = (const float*)d_in[9];
  const float* gamma = (const float*)d_in[10];
  const float* beta  = (const float*)d_in[11];
  float* out = (float*)d_out;

  const size_t MT = (size_t)4096 * 1024;  // tokens x hid
  const size_t WT = (size_t)1024 * 1024;
  char* ws = (char*)d_ws;
  u16* Xq  = (u16*)ws; ws += MT * 2;
  u16* Xkv = (u16*)ws; ws += MT * 2;
  u16* Wqt = (u16*)ws; ws += WT * 2;
  u16* Wkt = (u16*)ws; ws += WT * 2;
  u16* Wvt = (u16*)ws; ws += WT * 2;
  u16* Wot = (u16*)ws; ws += WT * 2;
  u16* Qp  = (u16*)ws; ws += MT * 2;
  u16* Kp  = (u16*)ws; ws += MT * 2;
  u16* Vp  = (u16*)ws; ws += MT * 2;
  u16* Ctx = (u16*)ws; ws += MT * 2;
  float* Xres = (float*)ws; ws += MT * 4;

  // casts
  cast_bf16_kernel<<<4096, 256, 0, stream>>>(query, Xq, (int)(MT / 4));
  cast_bf16_kernel<<<4096, 256, 0, stream>>>(key_value, Xkv, (int)(MT / 4));
  // weight transposes (W[K,N] -> Wt[N,K] bf16)
  dim3 tb(32, 8), tg(32, 32);
  transpose_cast_kernel<<<tg, tb, 0, stream>>>(Wq, Wqt, 1024, 1024);
  transpose_cast_kernel<<<tg, tb, 0, stream>>>(Wk, Wkt, 1024, 1024);
  transpose_cast_kernel<<<tg, tb, 0, stream>>>(Wv, Wvt, 1024, 1024);
  transpose_cast_kernel<<<tg, tb, 0, stream>>>(Wo, Wot, 1024, 1024);
  // projections (bf16 out)
  dim3 gg(8, 32);
  gemm_bf16_kernel<<<gg, 256, 0, stream>>>(Xq, Wqt, bq, nullptr, Qp, nullptr, 4096, 1024, 1024);
  gemm_bf16_kernel<<<gg, 256, 0, stream>>>(Xkv, Wkt, bk, nullptr, Kp, nullptr, 4096, 1024, 1024);
  gemm_bf16_kernel<<<gg, 256, 0, stream>>>(Xkv, Wvt, bv, nullptr, Vp, nullptr, 4096, 1024, 1024);
  // attention
  attn_kernel<<<dim3(32, 16, 2), 256, 0, stream>>>(Qp, Kp, Vp, Ctx);
  // output projection + residual (fp32 out)
  gemm_bf16_kernel<<<gg, 256, 0, stream>>>(Ctx, Wot, bo, query, nullptr, Xres, 4096, 1024, 1024);
  // layernorm
  ln_kernel<<<4096, 256, 0, stream>>>(Xres, gamma, beta, out);
}

// Round 2
// 309.449 us; speedup vs baseline: 1.4586x; 1.4586x over previous
//
#include <hip/hip_runtime.h>

typedef unsigned short u16;
typedef __bf16 bf16x8 __attribute__((ext_vector_type(8)));
typedef float f32x4 __attribute__((ext_vector_type(4)));
typedef unsigned short u16x4 __attribute__((ext_vector_type(4)));

#define LOG2E 1.44269504088896340736f

__device__ __forceinline__ u16 f2bf(float f) {
  unsigned u = __float_as_uint(f);
  u += 0x7FFFu + ((u >> 16) & 1u);
  return (u16)(u >> 16);
}

__device__ __forceinline__ void load_lds16(const void* g, void* l) {
  __builtin_amdgcn_global_load_lds(
      (__attribute__((address_space(1))) void*)g,
      (__attribute__((address_space(3))) void*)l, 16, 0, 0);
}

__device__ __forceinline__ f32x4 mfma16(bf16x8 a, bf16x8 b, f32x4 c) {
  return __builtin_amdgcn_mfma_f32_16x16x32_bf16(a, b, c, 0, 0, 0);
}

// ---------------- cast fp32 -> bf16 for query + key_value in one launch ----------
__global__ __launch_bounds__(256) void cast2_kernel(const float* __restrict__ q,
                                                    const float* __restrict__ kv,
                                                    u16* __restrict__ Xq,
                                                    u16* __restrict__ Xkv, int n4each) {
  int i = blockIdx.x * 256 + threadIdx.x;
  const float* src; u16* dst; int j;
  if (i < n4each) { src = q; dst = Xq; j = i; }
  else            { src = kv; dst = Xkv; j = i - n4each; }
  const float4 v = ((const float4*)src)[j];
  u16x4 o;
  o.x = f2bf(v.x); o.y = f2bf(v.y); o.z = f2bf(v.z); o.w = f2bf(v.w);
  ((u16x4*)dst)[j] = o;
}

// ---------------- transpose+cast all 4 weights: W[K,N] f32 -> Wt[N,K] bf16 -------
__global__ __launch_bounds__(256) void transpose_cast4_kernel(
    const float* __restrict__ Wq, const float* __restrict__ Wk,
    const float* __restrict__ Wv, const float* __restrict__ Wo,
    u16* __restrict__ Wqt, u16* __restrict__ Wkt,
    u16* __restrict__ Wvt, u16* __restrict__ Wot) {
  const float* W; u16* Wt;
  switch (blockIdx.z) {
    case 0: W = Wq; Wt = Wqt; break;
    case 1: W = Wk; Wt = Wkt; break;
    case 2: W = Wv; Wt = Wvt; break;
    default: W = Wo; Wt = Wot; break;
  }
  __shared__ float tile[32][33];
  const int tx = threadIdx.x & 31, ty = threadIdx.x >> 5;  // 32x8
  const int n0 = blockIdx.x * 32, k0 = blockIdx.y * 32;
#pragma unroll
  for (int i = 0; i < 4; i++)
    tile[ty + i * 8][tx] = W[(size_t)(k0 + ty + i * 8) * 1024 + n0 + tx];
  __syncthreads();
#pragma unroll
  for (int i = 0; i < 4; i++)
    Wt[(size_t)(n0 + ty + i * 8) * 1024 + k0 + tx] = f2bf(tile[tx][ty + i * 8]);
}

// ---------------- shared 128x128 MFMA GEMM tile: C = A[M,K] @ Bt[N,K]^T ----------
__device__ __forceinline__ void gemm_tile(
    const u16* __restrict__ A, int lda, const u16* __restrict__ Bt, int ldb,
    const float* __restrict__ bias, bool brow, float scale,
    const float* __restrict__ resid, u16* __restrict__ Cb, float* __restrict__ Cf,
    int ldc, int bm, int bn, int K) {
  __shared__ alignas(16) u16 As[128 * 32];
  __shared__ alignas(16) u16 Bs[128 * 32];
  const int tid = threadIdx.x;
  const int wave = tid >> 6, lane = tid & 63;
  const int lm = lane & 15, kq = lane >> 4;
  const int g1 = tid, g2 = tid + 256;
  const u16* Ag1 = A + (size_t)(bm + (g1 >> 2)) * lda + (g1 & 3) * 8;
  const u16* Ag2 = A + (size_t)(bm + (g2 >> 2)) * lda + (g2 & 3) * 8;
  const u16* Bg1 = Bt + (size_t)(bn + (g1 >> 2)) * ldb + (g1 & 3) * 8;
  const u16* Bg2 = Bt + (size_t)(bn + (g2 >> 2)) * ldb + (g2 & 3) * 8;
  u16* lA1 = &As[g1 * 8]; u16* lA2 = &As[g2 * 8];
  u16* lB1 = &Bs[g1 * 8]; u16* lB2 = &Bs[g2 * 8];
  const int wm = (wave >> 1) * 64, wn = (wave & 1) * 64;

  f32x4 acc[4][4] = {};
  for (int k0 = 0; k0 < K; k0 += 32) {
    __syncthreads();
    load_lds16(Ag1 + k0, lA1);
    load_lds16(Ag2 + k0, lA2);
    load_lds16(Bg1 + k0, lB1);
    load_lds16(Bg2 + k0, lB2);
    __syncthreads();
    bf16x8 a[4], b[4];
#pragma unroll
    for (int t = 0; t < 4; t++)
      a[t] = *(const bf16x8*)&As[(wm + t * 16 + lm) * 32 + kq * 8];
#pragma unroll
    for (int t = 0; t < 4; t++)
      b[t] = *(const bf16x8*)&Bs[(wn + t * 16 + lm) * 32 + kq * 8];
#pragma unroll
    for (int mt = 0; mt < 4; mt++)
#pragma unroll
      for (int nt = 0; nt < 4; nt++)
        acc[mt][nt] = mfma16(a[mt], b[nt], acc[mt][nt]);
  }
  // epilogue: C/D layout col=lane&15, row=(lane>>4)*4+r
#pragma unroll
  for (int mt = 0; mt < 4; mt++) {
    float rb[4];
#pragma unroll
    for (int r = 0; r < 4; r++)
      rb[r] = brow ? bias[bm + wm + mt * 16 + kq * 4 + r] : 0.f;
#pragma unroll
    for (int nt = 0; nt < 4; nt++) {
      const int col = bn + wn + nt * 16 + lm;
      const float cb = brow ? 0.f : bias[col];
#pragma unroll
      for (int r = 0; r < 4; r++) {
        const int row = bm + wm + mt * 16 + kq * 4 + r;
        const size_t idx = (size_t)row * ldc + col;
        const float v = (acc[mt][nt][r] + rb[r] + cb) * scale;
        if (Cf) Cf[idx] = v + resid[idx];
        else    Cb[idx] = f2bf(v);
      }
    }
  }
}

// ---- fused projections: blocks 0..255 Q-proj, 256..511 K-proj, 512..767 V^T ----
__global__ __launch_bounds__(256) void proj_gemm_kernel(
    const u16* __restrict__ Xq, const u16* __restrict__ Xkv,
    const u16* __restrict__ Wqt, const u16* __restrict__ Wkt, const u16* __restrict__ Wvt,
    const float* __restrict__ bq, const float* __restrict__ bk, const float* __restrict__ bv,
    u16* __restrict__ Qp, u16* __restrict__ Kp, u16* __restrict__ Vt, float qscale) {
  const int bid = blockIdx.x;
  const u16 *A, *Bt; const float* bias; u16* C;
  bool brow = false; float sc = 1.f; int ldc = 1024; int bm, bn;
  if (bid < 256) {
    A = Xq; Bt = Wqt; bias = bq; C = Qp; sc = qscale;
    bm = (bid >> 3) * 128; bn = (bid & 7) * 128;
  } else if (bid < 512) {
    const int r = bid - 256;
    A = Xkv; Bt = Wkt; bias = bk; C = Kp;
    bm = (r >> 3) * 128; bn = (r & 7) * 128;
  } else {
    int r = bid - 512;
    const int z = r >> 7; r &= 127;
    A = Wvt; Bt = Xkv + (size_t)z * 2048 * 1024; bias = bv; brow = true;
    C = Vt + (size_t)z * 1024 * 2048; ldc = 2048;
    bm = (r >> 4) * 128; bn = (r & 15) * 128;
  }
  gemm_tile(A, 1024, Bt, 1024, bias, brow, sc, nullptr, C, nullptr, ldc, bm, bn, 1024);
}

// ---- output projection + residual (fp32 out) ----
__global__ __launch_bounds__(256) void ogemm_kernel(
    const u16* __restrict__ Ctx, const u16* __restrict__ Wot,
    const float* __restrict__ bo, const float* __restrict__ query,
    float* __restrict__ Xres) {
  gemm_tile(Ctx, 1024, Wot, 1024, bo, false, 1.f, query, nullptr, Xres, 1024,
            blockIdx.y * 128, blockIdx.x * 128, 1024);
}

// ---------------- flash attention: 128 q / block, 32 q / wave, BKV=64 ----------
// K,V fragments straight from global (L1/L2); P via XOR-swizzled per-wave LDS.
// Q is pre-scaled by 0.125*log2(e) -> use exp2 directly.
__global__ __launch_bounds__(256) void attn_kernel(
    const u16* __restrict__ Qp, const u16* __restrict__ Kp,
    const u16* __restrict__ Vt, u16* __restrict__ ctx) {
  __shared__ alignas(16) u16 Ps[4][32 * 64];
  const int tid = threadIdx.x;
  const int wave = tid >> 6, lane = tid & 63;
  const int lm = lane & 15, kq = lane >> 4;
  const int b = blockIdx.z, h = blockIdx.y;
  const int q0 = blockIdx.x * 128 + wave * 32;

  const u16* Qb = Qp + (size_t)(b * 2048 + q0) * 1024 + h * 64;
  bf16x8 qf[2][2];
#pragma unroll
  for (int qb = 0; qb < 2; qb++)
#pragma unroll
    for (int s = 0; s < 2; s++)
      qf[qb][s] = *(const bf16x8*)(Qb + (size_t)(qb * 16 + lm) * 1024 + s * 32 + kq * 8);

  const u16* Kb = Kp + (size_t)(b * 2048) * 1024 + h * 64;
  const u16* Vb = Vt + (size_t)(b * 1024 + h * 64) * 2048;
  u16* Pw = Ps[wave];
  const int pswz = lm & 7;

  f32x4 o[2][4] = {};
  float mrow[2] = {-1e30f, -1e30f};
  float lrow[2] = {0.f, 0.f};

  for (int kv0 = 0; kv0 < 2048; kv0 += 64) {
    // ---- S^T = K . Q^T  (D[m=kv][n=q]) ----
    f32x4 st[2][4] = {};
#pragma unroll
    for (int s = 0; s < 2; s++) {
      bf16x8 kf[4];
#pragma unroll
      for (int kb = 0; kb < 4; kb++)
        kf[kb] = *(const bf16x8*)(Kb + (size_t)(kv0 + kb * 16 + lm) * 1024 + s * 32 + kq * 8);
#pragma unroll
      for (int kb = 0; kb < 4; kb++)
#pragma unroll
        for (int qb = 0; qb < 2; qb++)
          st[qb][kb] = mfma16(kf[kb], qf[qb][s], st[qb][kb]);
    }
    // ---- online softmax (values already in log2 domain) ----
#pragma unroll
    for (int qb = 0; qb < 2; qb++) {
      float mx = st[qb][0][0];
#pragma unroll
      for (int kb = 0; kb < 4; kb++)
#pragma unroll
        for (int r = 0; r < 4; r++) mx = fmaxf(mx, st[qb][kb][r]);
      mx = fmaxf(mx, __shfl_xor(mx, 16));
      mx = fmaxf(mx, __shfl_xor(mx, 32));
      const float mnew = fmaxf(mrow[qb], mx);
      const float alpha = __builtin_amdgcn_exp2f(mrow[qb] - mnew);
      mrow[qb] = mnew;
      float ls = 0.f;
#pragma unroll
      for (int kb = 0; kb < 4; kb++) {
        u16x4 pl;
#pragma unroll
        for (int r = 0; r < 4; r++) {
          const float p = __builtin_amdgcn_exp2f(st[qb][kb][r] - mnew);
          ls += p;
          pl[r] = f2bf(p);
        }
        // P[q][kv], 16B-granule XOR swizzle on kv: bank-conflict-free
        const int g = (kb * 2 + (kq >> 1)) ^ pswz;
        *(u16x4*)&Pw[(qb * 16 + lm) * 64 + g * 8 + (kq & 1) * 4] = pl;
      }
      ls += __shfl_xor(ls, 16);
      ls += __shfl_xor(ls, 32);
      lrow[qb] = lrow[qb] * alpha + ls;
      // rescale O rows (row q = kq*4+r in C-layout)
#pragma unroll
      for (int r = 0; r < 4; r++) {
        const float ar = __shfl(alpha, kq * 4 + r);
#pragma unroll
        for (int nb = 0; nb < 4; nb++) o[qb][nb][r] *= ar;
      }
    }
    // ---- O += P . V  (A=P from swizzled LDS, B=V^T frags from global) ----
#pragma unroll
    for (int s2 = 0; s2 < 2; s2++) {
      bf16x8 vf[4];
#pragma unroll
      for (int nb = 0; nb < 4; nb++)
        vf[nb] = *(const bf16x8*)(Vb + (size_t)(nb * 16 + lm) * 2048 + kv0 + s2 * 32 + kq * 8);
#pragma unroll
      for (int qb = 0; qb < 2; qb++) {
        const bf16x8 pf =
            *(const bf16x8*)&Pw[(qb * 16 + lm) * 64 + (((s2 * 4 + kq) ^ pswz) * 8)];
#pragma unroll
        for (int nb = 0; nb < 4; nb++)
          o[qb][nb] = mfma16(pf, vf[nb], o[qb][nb]);
      }
    }
  }
  // ---- normalize + store ----
#pragma unroll
  for (int qb = 0; qb < 2; qb++) {
#pragma unroll
    for (int r = 0; r < 4; r++) {
      const float lr = 1.f / __shfl(lrow[qb], kq * 4 + r);
      const size_t row = (size_t)(b * 2048 + q0 + qb * 16 + kq * 4 + r);
#pragma unroll
      for (int nb = 0; nb < 4; nb++)
        ctx[row * 1024 + h * 64 + nb * 16 + lm] = f2bf(o[qb][nb][r] * lr);
    }
  }
}

// ---------------- LayerNorm over last dim (1024), one block per row ----------------
__global__ __launch_bounds__(256) void ln_kernel(const float* __restrict__ x,
                                                 const float* __restrict__ gamma,
                                                 const float* __restrict__ beta,
                                                 float* __restrict__ out) {
  const int row = blockIdx.x;
  const int t = threadIdx.x;
  const float4 v = ((const float4*)(x + (size_t)row * 1024))[t];
  float s = v.x + v.y + v.z + v.w;
  float s2 = v.x * v.x + v.y * v.y + v.z * v.z + v.w * v.w;
#pragma unroll
  for (int m = 1; m < 64; m <<= 1) {
    s += __shfl_xor(s, m);
    s2 += __shfl_xor(s2, m);
  }
  __shared__ float red[8];
  const int wave = t >> 6, lane = t & 63;
  if (lane == 0) { red[wave] = s; red[4 + wave] = s2; }
  __syncthreads();
  s = red[0] + red[1] + red[2] + red[3];
  s2 = red[4] + red[5] + red[6] + red[7];
  const float mu = s * (1.f / 1024.f);
  const float var = s2 * (1.f / 1024.f) - mu * mu;
  const float rstd = rsqrtf(var + 1e-5f);
  const float4 gm = ((const float4*)gamma)[t];
  const float4 bt = ((const float4*)beta)[t];
  float4 o;
  o.x = (v.x - mu) * rstd * gm.x + bt.x;
  o.y = (v.y - mu) * rstd * gm.y + bt.y;
  o.z = (v.z - mu) * rstd * gm.z + bt.z;
  o.w = (v.w - mu) * rstd * gm.w + bt.w;
  ((float4*)(out + (size_t)row * 1024))[t] = o;
}

extern "C" void kernel_launch(void* const* d_in, const int* in_sizes, int n_in,
                              void* d_out, int out_size, void* d_ws, size_t ws_size,
                              hipStream_t stream) {
  const float* query     = (const float*)d_in[0];
  const float* key_value = (const float*)d_in[1];
  const float* Wq = (const float*)d_in[2];
  const float* bq = (const float*)d_in[3];
  const float* Wk = (const float*)d_in[4];
  const float* bk = (const float*)d_in[5];
  const float* Wv = (const float*)d_in[6];
  const float* bv = (const float*)d_in[7];
  const float* Wo = (const float*)d_in[8];
  const float* bo = (const float*)d_in[9];
  const float* gamma = (const float*)d_in[10];
  const float* beta  = (const float*)d_in[11];
  float* out = (float*)d_out;

  const size_t MT = (size_t)4096 * 1024;  // tokens x hid
  const size_t WT = (size_t)1024 * 1024;
  char* ws = (char*)d_ws;
  u16* Xq  = (u16*)ws; ws += MT * 2;
  u16* Xkv = (u16*)ws; ws += MT * 2;
  u16* Wqt = (u16*)ws; ws += WT * 2;
  u16* Wkt = (u16*)ws; ws += WT * 2;
  u16* Wvt = (u16*)ws; ws += WT * 2;
  u16* Wot = (u16*)ws; ws += WT * 2;
  u16* Qp  = (u16*)ws; ws += MT * 2;
  u16* Kp  = (u16*)ws; ws += MT * 2;
  u16* Vt  = (u16*)ws; ws += MT * 2;   // [b][hd(1024)][kv(2048)]
  u16* Ctx = (u16*)ws; ws += MT * 2;
  float* Xres = (float*)ws; ws += MT * 4;

  const float qscale = 0.125f * LOG2E;

  cast2_kernel<<<8192, 256, 0, stream>>>(query, key_value, Xq, Xkv, (int)(MT / 4));
  transpose_cast4_kernel<<<dim3(32, 32, 4), 256, 0, stream>>>(Wq, Wk, Wv, Wo, Wqt, Wkt, Wvt, Wot);
  proj_gemm_kernel<<<768, 256, 0, stream>>>(Xq, Xkv, Wqt, Wkt, Wvt, bq, bk, bv,
                                            Qp, Kp, Vt, qscale);
  attn_kernel<<<dim3(16, 16, 2), 256, 0, stream>>>(Qp, Kp, Vt, Ctx);
  ogemm_kernel<<<dim3(8, 32), 256, 0, stream>>>(Ctx, Wot, bo, query, Xres);
  ln_kernel<<<4096, 256, 0, stream>>>(Xres, gamma, beta, out);
}